// Round 14
// baseline (291.974 us; speedup 1.0000x reference)
//
#include <hip/hip_runtime.h>
#include <hip/hip_bf16.h>
#include <stdint.h>

#define NN 50000   // nodes
#define DI 128     // input features
#define DO 64      // output features
#define NE 800000  // edges per relation
#define NR 4       // relations
#define NB 782     // ceil(NN/64) 64-row buckets per relation
#define NBUCK (NR*NB)   // 3128 buckets total
#define PCHUNK 7168     // edges per place workgroup
#define PWG ((NE + PCHUNK - 1) / PCHUNK)   // 112 per relation
#define GEMMB ((NN + 127) / 128)   // 391 gemm blocks
#define ECAP 1408       // spmm2 per-relation bucket-run capacity (mean 1024, +12 sigma)

typedef short short8 __attribute__((ext_vector_type(8)));
typedef float f32x4  __attribute__((ext_vector_type(4)));
union FragU { uint4 u; short8 s; };

__device__ __forceinline__ uint32_t bfb(float f)
{
    __hip_bfloat16 h = __float2bfloat16(f);
    return (uint32_t)*reinterpret_cast<unsigned short*>(&h);
}

// ---------------------------------------------------------------------------
// Block-wide exclusive scan of a[0..N) in LDS. BLK threads, PER elems/thread.
// ---------------------------------------------------------------------------
template<int N, int PER, int BLK>
__device__ inline void block_exscan(int* a)
{
    __shared__ int wsum[BLK / 64];
    int tid = threadIdx.x;
    int base = tid * PER;
    int v[PER]; int s = 0;
    #pragma unroll
    for (int j = 0; j < PER; ++j) {
        int idx = base + j;
        int x = (idx < N) ? a[idx] : 0;
        v[j] = s; s += x;
    }
    int lane = tid & 63, wv = tid >> 6;
    int inc = s;
    #pragma unroll
    for (int off = 1; off < 64; off <<= 1) {
        int u = __shfl_up(inc, off);
        if (lane >= off) inc += u;
    }
    if (lane == 63) wsum[wv] = inc;
    __syncthreads();
    int woff = 0;
    for (int w = 0; w < wv; ++w) woff += wsum[w];
    int tb = woff + inc - s;
    #pragma unroll
    for (int j = 0; j < PER; ++j) {
        int idx = base + j;
        if (idx < N) a[idx] = tb + v[j];
    }
}

// ---------------------------------------------------------------------------
// K1: wtrans (blocks [0,128)) || bhist (blocks [128,256)).
// ---------------------------------------------------------------------------
__global__ __launch_bounds__(256) void prep_kernel(
    const float* __restrict__ W, const int* __restrict__ rows,
    uint16_t* __restrict__ wt, int* __restrict__ gtot)
{
    __shared__ int h[NB];
    int bid = blockIdx.x, tid = threadIdx.x;

    if (bid < 128) {
        int i = bid * 256 + tid;   // exactly 32768
        int r = i >> 13;
        int k = (i >> 6) & 127;
        int n = i & 63;
        wt[((size_t)(r * DO + n) << 7) + k] = (uint16_t)bfb(W[i]);
    } else {
        int bb = bid - 128;
        int r = bb >> 5, sub = bb & 31;
        for (int i = tid; i < NB; i += 256) h[i] = 0;
        __syncthreads();
        const int4* rr4 = (const int4*)(rows + (size_t)r * NE);
        for (int k = sub * 256 + tid; k < NE / 4; k += 32 * 256) {
            int4 v = rr4[k];
            atomicAdd(&h[v.x >> 6], 1);
            atomicAdd(&h[v.y >> 6], 1);
            atomicAdd(&h[v.z >> 6], 1);
            atomicAdd(&h[v.w >> 6], 1);
        }
        __syncthreads();
        int* gt = gtot + r * NB;
        for (int i = tid; i < NB; i += 256)
            if (h[i]) atomicAdd(&gt[i], h[i]);
    }
}

// ---------------------------------------------------------------------------
// K2: scan bucket totals -> gstart[0..NBUCK] + gcur copy. One block.
// ---------------------------------------------------------------------------
__global__ __launch_bounds__(512) void bases_kernel(
    const int* __restrict__ gtot, int* __restrict__ gstart,
    int* __restrict__ gcur)
{
    __shared__ int a[NBUCK + 1];
    int tid = threadIdx.x;
    for (int i = tid; i < NBUCK + 1; i += 512) a[i] = (i < NBUCK) ? gtot[i] : 0;
    __syncthreads();
    block_exscan<NBUCK + 1, 7, 512>(a);
    __syncthreads();
    for (int i = tid; i < NBUCK + 1; i += 512) {
        gstart[i] = a[i];
        if (i < NBUCK) gcur[i] = a[i];
    }
}

// ---------------------------------------------------------------------------
// K3: gemm (blocks [0,GEMMB)) || place (blocks [GEMMB, GEMMB+PWG*NR)).
// gemm: x f32 -> bf16 fragments in-register; MFMA 16x16x32; LDS-staged stores;
//       also reduces per-relation max|xw| into scl[r] (f32 bits atomicMax).
// place: bucket counting-sort of a PCHUNK chunk; record col:16|rowlow:6|bkt:10.
// ---------------------------------------------------------------------------
__global__ __launch_bounds__(512) void gemm_place_kernel(
    const float* __restrict__ x, const uint4* __restrict__ wt4,
    uint16_t* __restrict__ xwb, float* __restrict__ scl,
    const int* __restrict__ rows, const int* __restrict__ cols,
    const float* __restrict__ vals, int* __restrict__ gcur,
    int2* __restrict__ csr)
{
    __shared__ __align__(16) char smem[63616];
    int tid = threadIdx.x;

    if (blockIdx.x < GEMMB) {
        // ================= gemm role =================
        uint16_t* tile = (uint16_t*)smem;           // 16 KB
        int wv = __builtin_amdgcn_readfirstlane(tid >> 6);
        int lane = tid & 63;
        int n0 = blockIdx.x * 128 + wv * 16;
        int m16 = lane & 15, g = lane >> 4;
        bool act = (n0 < NN);                       // wave-uniform

        FragU af[4];
        if (act) {
            const float4* x4 = (const float4*)x;
            size_t rb = ((size_t)(n0 + m16) * DI) >> 2;
            #pragma unroll
            for (int ks = 0; ks < 4; ++ks) {
                float4 f0 = x4[rb + ks * 8 + g * 2];
                float4 f1 = x4[rb + ks * 8 + g * 2 + 1];
                af[ks].u.x = bfb(f0.x) | (bfb(f0.y) << 16);
                af[ks].u.y = bfb(f0.z) | (bfb(f0.w) << 16);
                af[ks].u.z = bfb(f1.x) | (bfb(f1.y) << 16);
                af[ks].u.w = bfb(f1.z) | (bfb(f1.w) << 16);
            }
        }

        int nrows = NN - blockIdx.x * 128; if (nrows > 128) nrows = 128;

        for (int r = 0; r < NR; ++r) {
            float lmax = 0.f;
            if (act) {
                #pragma unroll
                for (int ct = 0; ct < 4; ++ct) {
                    f32x4 acc = {0.f, 0.f, 0.f, 0.f};
                    #pragma unroll
                    for (int ks = 0; ks < 4; ++ks) {
                        FragU b;
                        b.u = wt4[(size_t)((r * DO + ct * 16 + m16) * 16) + ks * 4 + g];
                        acc = __builtin_amdgcn_mfma_f32_16x16x32_bf16(
                            af[ks].s, b.s, acc, 0, 0, 0);
                    }
                    #pragma unroll
                    for (int j = 0; j < 4; ++j) {
                        tile[(wv * 16 + g * 4 + j) * 64 + ct * 16 + m16] =
                            (uint16_t)bfb(acc[j]);
                        lmax = fmaxf(lmax, fabsf(acc[j]));
                    }
                }
            }
            // per-relation global max (uint-bits atomicMax, positives monotone)
            #pragma unroll
            for (int off = 32; off >= 1; off >>= 1)
                lmax = fmaxf(lmax, __shfl_xor(lmax, off));
            if (lane == 0)
                atomicMax((unsigned int*)(scl + r), __float_as_uint(lmax));
            __syncthreads();
            uint4* dst = (uint4*)(xwb + ((size_t)r * NN + blockIdx.x * 128) * 64);
            int tot = nrows * 8;
            for (int i = tid; i < tot; i += 512)
                dst[i] = ((const uint4*)tile)[i];
            __syncthreads();
        }
        return;
    }

    // ================= place role =================
    int* lofs  = (int*)smem;                        // (NB+1)*4 = 3132
    int* gbase = (int*)(smem + 3136);               // NB*4 = 3128
    int2* stag = (int2*)(smem + 6272);              // PCHUNK*8 = 57344
    int pb = blockIdx.x - GEMMB;
    int r = pb / PWG;
    int chunk = pb - r * PWG;
    int e0 = chunk * PCHUNK;
    int cnt = NE - e0; if (cnt > PCHUNK) cnt = PCHUNK;
    const int*   rr = rows + (size_t)r * NE + e0;
    const int*   cc = cols + (size_t)r * NE + e0;
    const float* vv = vals + (size_t)r * NE + e0;

    for (int i = tid; i <= NB; i += 512) lofs[i] = 0;
    __syncthreads();
    for (int k = tid; k < cnt; k += 512) atomicAdd(&lofs[rr[k] >> 6], 1);
    __syncthreads();
    block_exscan<NB + 1, 2, 512>(lofs);
    __syncthreads();
    for (int b = tid; b < NB; b += 512) {
        int c = lofs[b + 1] - lofs[b];
        if (c > 0) gbase[b] = atomicAdd(&gcur[r * NB + b], c);
    }
    __syncthreads();
    for (int k = tid; k < cnt; k += 512) {
        int row = rr[k];
        int b = row >> 6;
        int slot = atomicAdd(&lofs[b], 1);
        stag[slot] = make_int2((cc[k] & 0xFFFF) | ((row & 63) << 16) | (b << 22),
                               __float_as_int(vv[k]));
    }
    __syncthreads();
    for (int i = tid; i < cnt; i += 512) {
        int2 t = stag[i];
        unsigned b2 = ((unsigned)t.x) >> 22;
        int start = b2 ? lofs[b2 - 1] : 0;
        csr[gbase[b2] + (i - start)] = t;
    }
}

// ---------------------------------------------------------------------------
// K3.5: quantize xwb bf16 -> xq int8 with per-relation scale 127/scl[r].
// grid (ceil(NN*DO/8/256), NR); thread: uint4 in (8 bf16) -> uint2 out (8 i8).
// ---------------------------------------------------------------------------
__global__ __launch_bounds__(256) void quant_kernel(
    const uint4* __restrict__ xwb4, uint2* __restrict__ xq2,
    const float* __restrict__ scl)
{
    const int PER_REL = NN * DO / 8;   // 400000
    int r = blockIdx.y;
    float sinv = 127.0f / fmaxf(scl[r], 1e-20f);
    int i = blockIdx.x * 256 + threadIdx.x;
    if (i >= PER_REL) return;
    uint4 u = xwb4[(size_t)r * PER_REL + i];
    float f[8];
    f[0] = __uint_as_float(u.x << 16); f[1] = __uint_as_float(u.x & 0xFFFF0000u);
    f[2] = __uint_as_float(u.y << 16); f[3] = __uint_as_float(u.y & 0xFFFF0000u);
    f[4] = __uint_as_float(u.z << 16); f[5] = __uint_as_float(u.z & 0xFFFF0000u);
    f[6] = __uint_as_float(u.w << 16); f[7] = __uint_as_float(u.w & 0xFFFF0000u);
    uint32_t q[8];
    #pragma unroll
    for (int j = 0; j < 8; ++j) {
        int t = (int)rintf(f[j] * sinv);
        t = t > 127 ? 127 : (t < -127 ? -127 : t);
        q[j] = (uint32_t)t & 0xFFu;
    }
    uint2 o;
    o.x = q[0] | (q[1] << 8) | (q[2] << 16) | (q[3] << 24);
    o.y = q[4] | (q[5] << 8) | (q[6] << 16) | (q[7] << 24);
    xq2[(size_t)r * PER_REL + i] = o;
}

// ---------------------------------------------------------------------------
// K4: spmm2<Q8> — bucket-resident fused rowsort + SpMM + epilogue.
// Block = 64-row bucket, 512 thr. Stages the bucket's 4 relation runs into
// LDS counting-sorted by row (records rewritten to gather offsets; val
// pre-multiplied by scl[r]/127 when Q8), then quarter-wave-per-edge
// 2-stage-pipelined SpMM (64B int8 gathers when Q8) + fused epilogue.
// ---------------------------------------------------------------------------
template<int Q8>
__global__ __launch_bounds__(512) void spmm2_kernel(
    const uint2* __restrict__ xw2, const uint32_t* __restrict__ xq4,
    const int2* __restrict__ csr, const int* __restrict__ gstart,
    const float* __restrict__ scl, const float* __restrict__ bias,
    float* __restrict__ out)
{
    __shared__ int2 ebuf[NR][ECAP];     // 45056 B
    __shared__ int rcnt[NR][64];
    __shared__ int rofs[NR][64];
    __shared__ int rcur[NR][64];
    int tid = threadIdx.x, blk = blockIdx.x;
    int wv = __builtin_amdgcn_readfirstlane(tid >> 6);
    int lane = tid & 63;

    float sfac[NR];
    #pragma unroll
    for (int r = 0; r < NR; ++r)
        sfac[r] = Q8 ? scl[r] * (1.0f / 127.0f) : 1.0f;

    if (tid < 256) rcnt[tid >> 6][tid & 63] = 0;
    __syncthreads();

    // ---- load runs into registers + row histogram ----
    int sbeg[NR], cnt[NR], scnt[NR];
    int2 ed[NR][3];                     // ceil(ECAP/512)=3 per relation
    #pragma unroll
    for (int r = 0; r < NR; ++r) {
        int b = r * NB + blk;
        sbeg[r] = gstart[b];
        cnt[r]  = gstart[b + 1] - sbeg[r];
        scnt[r] = cnt[r] > ECAP ? ECAP : cnt[r];
        #pragma unroll
        for (int j = 0; j < 3; ++j) {
            int i = tid + j * 512;
            if (i < scnt[r]) {
                ed[r][j] = csr[sbeg[r] + i];
                atomicAdd(&rcnt[r][(ed[r][j].x >> 16) & 63], 1);
            }
        }
    }
    __syncthreads();

    // ---- per-relation 64-bin exscan (wave r handles relation r) ----
    if (wv < NR) {
        int c = rcnt[wv][lane];
        int inc = c;
        #pragma unroll
        for (int off = 1; off < 64; off <<= 1) {
            int u = __shfl_up(inc, off);
            if (lane >= off) inc += u;
        }
        rofs[wv][lane] = inc - c;
        rcur[wv][lane] = inc - c;
    }
    __syncthreads();

    // ---- scatter into ebuf row-sorted: (gather-ofs, val*sfac) ----
    #pragma unroll
    for (int r = 0; r < NR; ++r) {
        #pragma unroll
        for (int j = 0; j < 3; ++j) {
            int i = tid + j * 512;
            if (i < scnt[r]) {
                int rl = (ed[r][j].x >> 16) & 63;
                int slot = atomicAdd(&rcur[r][rl], 1);
                float v = __int_as_float(ed[r][j].y) * sfac[r];
                ebuf[r][slot] = make_int2((r * NN + (ed[r][j].x & 0xFFFF)) << 4,
                                          __float_as_int(v));
            }
        }
    }
    __syncthreads();

    // ---- SpMM: wave wv processes rows wv*8 .. wv*8+7 ----
    int e4 = lane >> 4, fq = lane & 15;
    float4 br[NR];
    #pragma unroll
    for (int r = 0; r < NR; ++r)
        br[r] = *(const float4*)&bias[r * DO + 4 * fq];

    for (int mi = 0; mi < 8; ++mi) {
        int m = wv * 8 + mi;
        int n = blk * 64 + m;
        if (n >= NN) break;             // wave-uniform

        int st[NR], dc[NR], dege[NR];
        int maxdeg = 0;
        #pragma unroll
        for (int r = 0; r < NR; ++r) {
            st[r] = rofs[r][m];
            dc[r] = rcnt[r][m];
            dege[r] = (dc[r] + 3) & ~3;
            maxdeg = max(maxdeg, dege[r]);
        }

        float a[NR][4];
        #pragma unroll
        for (int r = 0; r < NR; ++r)
            #pragma unroll
            for (int j = 0; j < 4; ++j) a[r][j] = 0.f;

        float vA[NR]; uint2 uA[NR];
        float vB[NR]; uint2 uB[NR];

        // stage issue k=0 into A
        #pragma unroll
        for (int r = 0; r < NR; ++r) {
            if (0 < dege[r]) {
                int e = e4; int ec = e < dc[r] ? e : dc[r] - 1;
                int2 cv = ebuf[r][st[r] + ec];
                vA[r] = (e < dc[r]) ? __int_as_float(cv.y) : 0.f;
                if (Q8) uA[r].x = xq4[cv.x + fq]; else uA[r] = xw2[cv.x + fq];
            } else { vA[r] = 0.f; uA[r] = make_uint2(0u, 0u); }
        }
        for (int k = 0; k < maxdeg; k += 8) {
            #pragma unroll
            for (int r = 0; r < NR; ++r) {          // issue k+4 -> B
                int kk = k + 4;
                if (kk < dege[r]) {
                    int e = kk + e4; int ec = e < dc[r] ? e : dc[r] - 1;
                    int2 cv = ebuf[r][st[r] + ec];
                    vB[r] = (e < dc[r]) ? __int_as_float(cv.y) : 0.f;
                    if (Q8) uB[r].x = xq4[cv.x + fq]; else uB[r] = xw2[cv.x + fq];
                } else { vB[r] = 0.f; uB[r] = make_uint2(0u, 0u); }
            }
            #pragma unroll
            for (int r = 0; r < NR; ++r) {          // consume A
                float v = vA[r];
                if (Q8) {
                    uint32_t u = uA[r].x;
                    a[r][0] = fmaf(v, (float)(((int)(u << 24)) >> 24), a[r][0]);
                    a[r][1] = fmaf(v, (float)(((int)(u << 16)) >> 24), a[r][1]);
                    a[r][2] = fmaf(v, (float)(((int)(u <<  8)) >> 24), a[r][2]);
                    a[r][3] = fmaf(v, (float)(((int)u) >> 24),         a[r][3]);
                } else {
                    a[r][0] = fmaf(v, __uint_as_float(uA[r].x << 16),         a[r][0]);
                    a[r][1] = fmaf(v, __uint_as_float(uA[r].x & 0xFFFF0000u), a[r][1]);
                    a[r][2] = fmaf(v, __uint_as_float(uA[r].y << 16),         a[r][2]);
                    a[r][3] = fmaf(v, __uint_as_float(uA[r].y & 0xFFFF0000u), a[r][3]);
                }
            }
            #pragma unroll
            for (int r = 0; r < NR; ++r) {          // issue k+8 -> A
                int kk = k + 8;
                if (kk < dege[r]) {
                    int e = kk + e4; int ec = e < dc[r] ? e : dc[r] - 1;
                    int2 cv = ebuf[r][st[r] + ec];
                    vA[r] = (e < dc[r]) ? __int_as_float(cv.y) : 0.f;
                    if (Q8) uA[r].x = xq4[cv.x + fq]; else uA[r] = xw2[cv.x + fq];
                } else { vA[r] = 0.f; uA[r] = make_uint2(0u, 0u); }
            }
            #pragma unroll
            for (int r = 0; r < NR; ++r) {          // consume B
                float v = vB[r];
                if (Q8) {
                    uint32_t u = uB[r].x;
                    a[r][0] = fmaf(v, (float)(((int)(u << 24)) >> 24), a[r][0]);
                    a[r][1] = fmaf(v, (float)(((int)(u << 16)) >> 24), a[r][1]);
                    a[r][2] = fmaf(v, (float)(((int)(u <<  8)) >> 24), a[r][2]);
                    a[r][3] = fmaf(v, (float)(((int)u) >> 24),         a[r][3]);
                } else {
                    a[r][0] = fmaf(v, __uint_as_float(uB[r].x << 16),         a[r][0]);
                    a[r][1] = fmaf(v, __uint_as_float(uB[r].x & 0xFFFF0000u), a[r][1]);
                    a[r][2] = fmaf(v, __uint_as_float(uB[r].y << 16),         a[r][2]);
                    a[r][3] = fmaf(v, __uint_as_float(uB[r].y & 0xFFFF0000u), a[r][3]);
                }
            }
        }

        // overflow tail (cnt>ECAP: ~never; scan unstaged edges from global)
        #pragma unroll
        for (int r = 0; r < NR; ++r) {
            if (cnt[r] > ECAP) {                    // wave-uniform
                for (int i = sbeg[r] + ECAP; i < sbeg[r] + cnt[r]; ++i) {
                    int2 cv = csr[i];
                    int rl = (cv.x >> 16) & 63;
                    float v = (rl == m && lane < 16)
                              ? __int_as_float(cv.y) * sfac[r] : 0.f;
                    int ofs = (int)((((size_t)r * NN + (cv.x & 0xFFFF)) << 4) + fq);
                    if (Q8) {
                        uint32_t u = xq4[ofs];
                        a[r][0] = fmaf(v, (float)(((int)(u << 24)) >> 24), a[r][0]);
                        a[r][1] = fmaf(v, (float)(((int)(u << 16)) >> 24), a[r][1]);
                        a[r][2] = fmaf(v, (float)(((int)(u <<  8)) >> 24), a[r][2]);
                        a[r][3] = fmaf(v, (float)(((int)u) >> 24),         a[r][3]);
                    } else {
                        uint2 u = xw2[ofs];
                        a[r][0] = fmaf(v, __uint_as_float(u.x << 16),         a[r][0]);
                        a[r][1] = fmaf(v, __uint_as_float(u.x & 0xFFFF0000u), a[r][1]);
                        a[r][2] = fmaf(v, __uint_as_float(u.y << 16),         a[r][2]);
                        a[r][3] = fmaf(v, __uint_as_float(u.y & 0xFFFF0000u), a[r][3]);
                    }
                }
            }
        }

        // epilogue: reduce edge-groups, bias+relu+sum, L2 normalize
        float t[4] = {0.f, 0.f, 0.f, 0.f};
        #pragma unroll
        for (int r = 0; r < NR; ++r) {
            #pragma unroll
            for (int j = 0; j < 4; ++j) {
                a[r][j] += __shfl_xor(a[r][j], 16);
                a[r][j] += __shfl_xor(a[r][j], 32);
            }
            t[0] += fmaxf(a[r][0] + br[r].x, 0.f);
            t[1] += fmaxf(a[r][1] + br[r].y, 0.f);
            t[2] += fmaxf(a[r][2] + br[r].z, 0.f);
            t[3] += fmaxf(a[r][3] + br[r].w, 0.f);
        }
        float s2 = t[0]*t[0] + t[1]*t[1] + t[2]*t[2] + t[3]*t[3];
        #pragma unroll
        for (int off = 8; off >= 1; off >>= 1) s2 += __shfl_xor(s2, off);
        float inv = 1.0f / fmaxf(sqrtf(s2), 1e-12f);
        if (lane < 16) {
            float4 o = make_float4(t[0]*inv, t[1]*inv, t[2]*inv, t[3]*inv);
            *(float4*)&out[(size_t)n * DO + 4 * fq] = o;
        }
    }
}

// ---------------------------------------------------------------------------
// Fallback path (small ws): R1 atomic-scatter pipeline.
// ---------------------------------------------------------------------------
__global__ __launch_bounds__(256) void gemm_kernel(
    const float* __restrict__ x, const float* __restrict__ W,
    __hip_bfloat16* __restrict__ xwb)
{
    __shared__ float Wl[DI * DO];
    for (int i = threadIdx.x; i < DI * DO; i += 256) Wl[i] = W[i];
    __syncthreads();

    int wv   = __builtin_amdgcn_readfirstlane((int)(threadIdx.x >> 6));
    int lane = threadIdx.x & 63;
    int n0   = blockIdx.x * 32 + wv * 8;
    if (n0 >= NN) return;
    int nrows = NN - n0; if (nrows > 8) nrows = 8;

    if (nrows == 8) {
        const float* xr = x + (size_t)n0 * DI;
        float acc[8] = {0.f,0.f,0.f,0.f,0.f,0.f,0.f,0.f};
        #pragma unroll 8
        for (int k = 0; k < DI; ++k) {
            float w = Wl[k * DO + lane];
            #pragma unroll
            for (int rr = 0; rr < 8; ++rr)
                acc[rr] = fmaf(xr[(size_t)rr * DI + k], w, acc[rr]);
        }
        #pragma unroll
        for (int rr = 0; rr < 8; ++rr)
            xwb[(size_t)(n0 + rr) * DO + lane] = __float2bfloat16(acc[rr]);
    } else {
        for (int rr = 0; rr < nrows; ++rr) {
            const float* xr = x + (size_t)(n0 + rr) * DI;
            float acc = 0.f;
            for (int k = 0; k < DI; ++k)
                acc = fmaf(xr[k], Wl[k * DO + lane], acc);
            xwb[(size_t)(n0 + rr) * DO + lane] = __float2bfloat16(acc);
        }
    }
}

__global__ __launch_bounds__(256) void scatter_kernel(
    const __hip_bfloat16* __restrict__ xwb, const float* __restrict__ vals,
    const int* __restrict__ rows, const int* __restrict__ cols,
    float* __restrict__ agg)
{
    const int nPairs = NE / 2;
    int gwave  = (blockIdx.x * 256 + threadIdx.x) >> 6;
    int half   = (threadIdx.x >> 5) & 1;
    int l32    = threadIdx.x & 31;
    int stride = gridDim.x * 4;
    const uint16_t* xw16 = reinterpret_cast<const uint16_t*>(xwb);
    for (int p = gwave; p < nPairs; p += stride) {
        int e = 2 * p + half;
        int row = rows[e]; int col = cols[e]; float v = vals[e];
        uint32_t packed = *reinterpret_cast<const uint32_t*>(
            xw16 + ((size_t)col << 6) + 2 * l32);
        float f0 = __uint_as_float(packed << 16);
        float f1 = __uint_as_float(packed & 0xFFFF0000u);
        float* dst = agg + ((size_t)row << 6) + 2 * l32;
        atomicAdd(dst,     v * f0);
        atomicAdd(dst + 1, v * f1);
    }
}

__global__ __launch_bounds__(256) void accum_kernel(
    float* __restrict__ agg, const float* __restrict__ b,
    float* __restrict__ out, int first)
{
    int i = blockIdx.x * 256 + threadIdx.x;
    if (i >= NN * DO) return;
    float v = agg[i] + b[i & (DO - 1)];
    agg[i] = 0.f;
    v = fmaxf(v, 0.f);
    out[i] = first ? v : (out[i] + v);
}

__global__ __launch_bounds__(256) void norm_kernel(float* __restrict__ out)
{
    int n = (blockIdx.x * 256 + threadIdx.x) >> 6;
    int lane = threadIdx.x & 63;
    if (n >= NN) return;
    size_t idx = (size_t)n * DO + lane;
    float t = out[idx];
    float s = t * t;
    #pragma unroll
    for (int off = 32; off >= 1; off >>= 1) s += __shfl_xor(s, off);
    out[idx] = t / fmaxf(sqrtf(s), 1e-12f);
}

extern "C" void kernel_launch(void* const* d_in, const int* in_sizes, int n_in,
                              void* d_out, int out_size, void* d_ws, size_t ws_size,
                              hipStream_t stream)
{
    const float* x    = (const float*)d_in[0];
    const float* W    = (const float*)d_in[1];
    const float* b    = (const float*)d_in[2];
    const float* vals = (const float*)d_in[3];
    const int*   rows = (const int*)d_in[4];
    const int*   cols = (const int*)d_in[5];
    float* out = (float*)d_out;
    char* ws = (char*)d_ws;

    // ws: xwb 25.6MB | csr 25.6MB | gtot | scl | gstart | gcur | wt | xq 12.8MB
    const size_t O_XW = 0;
    const size_t O_CS = O_XW + (size_t)NR * NN * DO * 2;
    const size_t O_GT = O_CS + (size_t)NR * NE * 8;
    const size_t O_SC = O_GT + (size_t)NBUCK * 4;       // 16 B (zeroed w/ gtot)
    const size_t O_GS = O_SC + 16;
    const size_t O_GC = O_GS + (size_t)(NBUCK + 1) * 4;
    const size_t O_WT = O_GC + (size_t)NBUCK * 4;       // bf16 W^T, 64KB
    const size_t O_XQ = O_WT + 65536;                   // int8 xw, 12.8MB
    const size_t NEED0 = O_XQ;                          // bf16 tier
    const size_t NEED1 = O_XQ + (size_t)NR * NN * DO;   // int8 tier

    if (ws_size >= NEED0) {
        __hip_bfloat16* xwb = (__hip_bfloat16*)(ws + O_XW);
        int2* csr   = (int2*)(ws + O_CS);
        int* gtot   = (int*)(ws + O_GT);
        float* scl  = (float*)(ws + O_SC);
        int* gstart = (int*)(ws + O_GS);
        int* gcur   = (int*)(ws + O_GC);
        uint16_t* wt = (uint16_t*)(ws + O_WT);
        char* xq    = ws + O_XQ;
        bool q8 = (ws_size >= NEED1);

        hipMemsetAsync(gtot, 0, (size_t)NBUCK * 4 + 16, stream);
        prep_kernel<<<dim3(256), dim3(256), 0, stream>>>(W, rows, wt, gtot);
        bases_kernel<<<dim3(1), dim3(512), 0, stream>>>(gtot, gstart, gcur);
        gemm_place_kernel<<<dim3(GEMMB + PWG * NR), dim3(512), 0, stream>>>(
            x, (const uint4*)wt, (uint16_t*)xwb, scl,
            rows, cols, vals, gcur, csr);
        if (q8) {
            quant_kernel<<<dim3((NN * DO / 8 + 255) / 256, NR), dim3(256), 0, stream>>>(
                (const uint4*)xwb, (uint2*)xq, scl);
            spmm2_kernel<1><<<dim3(NB), dim3(512), 0, stream>>>(
                (const uint2*)xwb, (const uint32_t*)xq, csr, gstart, scl, b, out);
        } else {
            spmm2_kernel<0><<<dim3(NB), dim3(512), 0, stream>>>(
                (const uint2*)xwb, (const uint32_t*)xq, csr, gstart, scl, b, out);
        }
    } else {
        // sequential atomic-scatter fallback (19.2MB)
        __hip_bfloat16* xwb = (__hip_bfloat16*)ws;
        float* agg = (float*)(ws + (size_t)NN * DO * 2);
        hipMemsetAsync(agg, 0, (size_t)NN * DO * 4, stream);
        for (int r = 0; r < NR; ++r) {
            gemm_kernel<<<dim3((NN + 31) / 32), dim3(256), 0, stream>>>(
                x, W + (size_t)r * DI * DO, xwb);
            scatter_kernel<<<dim3(2048), dim3(256), 0, stream>>>(
                xwb, vals + (size_t)r * NE, rows + (size_t)r * NE,
                cols + (size_t)r * NE, agg);
            accum_kernel<<<dim3((NN * DO + 255) / 256), dim3(256), 0, stream>>>(
                agg, b + (size_t)r * DO, out, r == 0);
        }
        norm_kernel<<<dim3((NN * DO + 255) / 256), dim3(256), 0, stream>>>(out);
    }
}

// Round 15
// 187.443 us; speedup vs baseline: 1.5577x; 1.5577x over previous
//
#include <hip/hip_runtime.h>
#include <hip/hip_bf16.h>
#include <stdint.h>

#define NN 50000   // nodes
#define DI 128     // input features
#define DO 64      // output features
#define NE 800000  // edges per relation
#define NR 4       // relations
#define NB 782     // ceil(NN/64) 64-row buckets per relation
#define NBUCK (NR*NB)   // 3128 buckets total
#define PCHUNK 7168     // edges per place workgroup
#define PWG ((NE + PCHUNK - 1) / PCHUNK)   // 112 per relation
#define GEMMB ((NN + 127) / 128)   // 391 gemm blocks
#define ECAP 1408       // spmm2 per-relation bucket-run capacity (mean 1024, +12 sigma)

typedef short short8 __attribute__((ext_vector_type(8)));
typedef float f32x4  __attribute__((ext_vector_type(4)));
union FragU { uint4 u; short8 s; };

__device__ __forceinline__ uint32_t bfb(float f)
{
    __hip_bfloat16 h = __float2bfloat16(f);
    return (uint32_t)*reinterpret_cast<unsigned short*>(&h);
}

// ---------------------------------------------------------------------------
// Block-wide exclusive scan of a[0..N) in LDS. BLK threads, PER elems/thread.
// ---------------------------------------------------------------------------
template<int N, int PER, int BLK>
__device__ inline void block_exscan(int* a)
{
    __shared__ int wsum[BLK / 64];
    int tid = threadIdx.x;
    int base = tid * PER;
    int v[PER]; int s = 0;
    #pragma unroll
    for (int j = 0; j < PER; ++j) {
        int idx = base + j;
        int x = (idx < N) ? a[idx] : 0;
        v[j] = s; s += x;
    }
    int lane = tid & 63, wv = tid >> 6;
    int inc = s;
    #pragma unroll
    for (int off = 1; off < 64; off <<= 1) {
        int u = __shfl_up(inc, off);
        if (lane >= off) inc += u;
    }
    if (lane == 63) wsum[wv] = inc;
    __syncthreads();
    int woff = 0;
    for (int w = 0; w < wv; ++w) woff += wsum[w];
    int tb = woff + inc - s;
    #pragma unroll
    for (int j = 0; j < PER; ++j) {
        int idx = base + j;
        if (idx < N) a[idx] = tb + v[j];
    }
}

// ---------------------------------------------------------------------------
// K1: wtrans (blocks [0,128)) || bhist (blocks [128,256)).
// ---------------------------------------------------------------------------
__global__ __launch_bounds__(256) void prep_kernel(
    const float* __restrict__ W, const int* __restrict__ rows,
    uint16_t* __restrict__ wt, int* __restrict__ gtot)
{
    __shared__ int h[NB];
    int bid = blockIdx.x, tid = threadIdx.x;

    if (bid < 128) {
        int i = bid * 256 + tid;   // exactly 32768
        int r = i >> 13;
        int k = (i >> 6) & 127;
        int n = i & 63;
        wt[((size_t)(r * DO + n) << 7) + k] = (uint16_t)bfb(W[i]);
    } else {
        int bb = bid - 128;
        int r = bb >> 5, sub = bb & 31;
        for (int i = tid; i < NB; i += 256) h[i] = 0;
        __syncthreads();
        const int4* rr4 = (const int4*)(rows + (size_t)r * NE);
        for (int k = sub * 256 + tid; k < NE / 4; k += 32 * 256) {
            int4 v = rr4[k];
            atomicAdd(&h[v.x >> 6], 1);
            atomicAdd(&h[v.y >> 6], 1);
            atomicAdd(&h[v.z >> 6], 1);
            atomicAdd(&h[v.w >> 6], 1);
        }
        __syncthreads();
        int* gt = gtot + r * NB;
        for (int i = tid; i < NB; i += 256)
            if (h[i]) atomicAdd(&gt[i], h[i]);
    }
}

// ---------------------------------------------------------------------------
// K2: scan bucket totals -> gstart[0..NBUCK] + gcur copy. One block.
// ---------------------------------------------------------------------------
__global__ __launch_bounds__(512) void bases_kernel(
    const int* __restrict__ gtot, int* __restrict__ gstart,
    int* __restrict__ gcur)
{
    __shared__ int a[NBUCK + 1];
    int tid = threadIdx.x;
    for (int i = tid; i < NBUCK + 1; i += 512) a[i] = (i < NBUCK) ? gtot[i] : 0;
    __syncthreads();
    block_exscan<NBUCK + 1, 7, 512>(a);
    __syncthreads();
    for (int i = tid; i < NBUCK + 1; i += 512) {
        gstart[i] = a[i];
        if (i < NBUCK) gcur[i] = a[i];
    }
}

// ---------------------------------------------------------------------------
// K3: gemm (blocks [0,GEMMB)) || place (blocks [GEMMB, GEMMB+PWG*NR)).
// EXACT R12 version (no in-kernel scale reduction — that was the R14 poison:
// hot-address device atomicMax + barrier coupling serialized all waves).
// ---------------------------------------------------------------------------
__global__ __launch_bounds__(512) void gemm_place_kernel(
    const float* __restrict__ x, const uint4* __restrict__ wt4,
    uint16_t* __restrict__ xwb,
    const int* __restrict__ rows, const int* __restrict__ cols,
    const float* __restrict__ vals, int* __restrict__ gcur,
    int2* __restrict__ csr)
{
    __shared__ __align__(16) char smem[63616];
    int tid = threadIdx.x;

    if (blockIdx.x < GEMMB) {
        // ================= gemm role =================
        uint16_t* tile = (uint16_t*)smem;           // 16 KB
        int wv = __builtin_amdgcn_readfirstlane(tid >> 6);
        int lane = tid & 63;
        int n0 = blockIdx.x * 128 + wv * 16;
        int m16 = lane & 15, g = lane >> 4;
        bool act = (n0 < NN);                       // wave-uniform

        FragU af[4];
        if (act) {
            const float4* x4 = (const float4*)x;
            size_t rb = ((size_t)(n0 + m16) * DI) >> 2;
            #pragma unroll
            for (int ks = 0; ks < 4; ++ks) {
                float4 f0 = x4[rb + ks * 8 + g * 2];
                float4 f1 = x4[rb + ks * 8 + g * 2 + 1];
                af[ks].u.x = bfb(f0.x) | (bfb(f0.y) << 16);
                af[ks].u.y = bfb(f0.z) | (bfb(f0.w) << 16);
                af[ks].u.z = bfb(f1.x) | (bfb(f1.y) << 16);
                af[ks].u.w = bfb(f1.z) | (bfb(f1.w) << 16);
            }
        }

        int nrows = NN - blockIdx.x * 128; if (nrows > 128) nrows = 128;

        for (int r = 0; r < NR; ++r) {
            if (act) {
                #pragma unroll
                for (int ct = 0; ct < 4; ++ct) {
                    f32x4 acc = {0.f, 0.f, 0.f, 0.f};
                    #pragma unroll
                    for (int ks = 0; ks < 4; ++ks) {
                        FragU b;
                        b.u = wt4[(size_t)((r * DO + ct * 16 + m16) * 16) + ks * 4 + g];
                        acc = __builtin_amdgcn_mfma_f32_16x16x32_bf16(
                            af[ks].s, b.s, acc, 0, 0, 0);
                    }
                    #pragma unroll
                    for (int j = 0; j < 4; ++j)
                        tile[(wv * 16 + g * 4 + j) * 64 + ct * 16 + m16] =
                            (uint16_t)bfb(acc[j]);
                }
            }
            __syncthreads();
            uint4* dst = (uint4*)(xwb + ((size_t)r * NN + blockIdx.x * 128) * 64);
            int tot = nrows * 8;
            for (int i = tid; i < tot; i += 512)
                dst[i] = ((const uint4*)tile)[i];
            __syncthreads();
        }
        return;
    }

    // ================= place role =================
    int* lofs  = (int*)smem;                        // (NB+1)*4 = 3132
    int* gbase = (int*)(smem + 3136);               // NB*4 = 3128
    int2* stag = (int2*)(smem + 6272);              // PCHUNK*8 = 57344
    int pb = blockIdx.x - GEMMB;
    int r = pb / PWG;
    int chunk = pb - r * PWG;
    int e0 = chunk * PCHUNK;
    int cnt = NE - e0; if (cnt > PCHUNK) cnt = PCHUNK;
    const int*   rr = rows + (size_t)r * NE + e0;
    const int*   cc = cols + (size_t)r * NE + e0;
    const float* vv = vals + (size_t)r * NE + e0;

    for (int i = tid; i <= NB; i += 512) lofs[i] = 0;
    __syncthreads();
    for (int k = tid; k < cnt; k += 512) atomicAdd(&lofs[rr[k] >> 6], 1);
    __syncthreads();
    block_exscan<NB + 1, 2, 512>(lofs);
    __syncthreads();
    for (int b = tid; b < NB; b += 512) {
        int c = lofs[b + 1] - lofs[b];
        if (c > 0) gbase[b] = atomicAdd(&gcur[r * NB + b], c);
    }
    __syncthreads();
    for (int k = tid; k < cnt; k += 512) {
        int row = rr[k];
        int b = row >> 6;
        int slot = atomicAdd(&lofs[b], 1);
        stag[slot] = make_int2((cc[k] & 0xFFFF) | ((row & 63) << 16) | (b << 22),
                               __float_as_int(vv[k]));
    }
    __syncthreads();
    for (int i = tid; i < cnt; i += 512) {
        int2 t = stag[i];
        unsigned b2 = ((unsigned)t.x) >> 22;
        int start = b2 ? lofs[b2 - 1] : 0;
        csr[gbase[b2] + (i - start)] = t;
    }
}

// ---------------------------------------------------------------------------
// K3.2: per-relation max|xw| -> scl[r] (float bits). Streaming 25.6MB.
// bf16 magnitude compare == integer compare on sign-cleared bits.
// One atomicMax per block (256 total) — no barrier coupling.
// ---------------------------------------------------------------------------
__global__ __launch_bounds__(256) void maxred_kernel(
    const uint4* __restrict__ xwb4, float* __restrict__ scl)
{
    const int PER_REL = NN * DO / 8;   // 400000 uint4
    int r = blockIdx.y;
    uint32_t m = 0;
    for (int i = blockIdx.x * 256 + threadIdx.x; i < PER_REL; i += gridDim.x * 256) {
        uint4 u = xwb4[(size_t)r * PER_REL + i];
        uint32_t a0 = u.x & 0x7FFF7FFFu, a1 = u.y & 0x7FFF7FFFu;
        uint32_t a2 = u.z & 0x7FFF7FFFu, a3 = u.w & 0x7FFF7FFFu;
        m = max(m, max(max(a0 & 0xFFFFu, a0 >> 16), max(a1 & 0xFFFFu, a1 >> 16)));
        m = max(m, max(max(a2 & 0xFFFFu, a2 >> 16), max(a3 & 0xFFFFu, a3 >> 16)));
    }
    #pragma unroll
    for (int off = 32; off >= 1; off >>= 1)
        m = max(m, (uint32_t)__shfl_xor((int)m, off));
    __shared__ uint32_t wmax[4];
    int lane = threadIdx.x & 63, wv = threadIdx.x >> 6;
    if (lane == 0) wmax[wv] = m;
    __syncthreads();
    if (threadIdx.x == 0) {
        m = max(max(wmax[0], wmax[1]), max(wmax[2], wmax[3]));
        atomicMax((unsigned int*)(scl + r), m << 16);   // bf16 bits -> f32 bits
    }
}

// ---------------------------------------------------------------------------
// K3.5: quantize xwb bf16 -> xq int8 with per-relation scale 127/scl[r].
// ---------------------------------------------------------------------------
__global__ __launch_bounds__(256) void quant_kernel(
    const uint4* __restrict__ xwb4, uint2* __restrict__ xq2,
    const float* __restrict__ scl)
{
    const int PER_REL = NN * DO / 8;   // 400000
    int r = blockIdx.y;
    float sinv = 127.0f / fmaxf(scl[r], 1e-20f);
    int i = blockIdx.x * 256 + threadIdx.x;
    if (i >= PER_REL) return;
    uint4 u = xwb4[(size_t)r * PER_REL + i];
    float f[8];
    f[0] = __uint_as_float(u.x << 16); f[1] = __uint_as_float(u.x & 0xFFFF0000u);
    f[2] = __uint_as_float(u.y << 16); f[3] = __uint_as_float(u.y & 0xFFFF0000u);
    f[4] = __uint_as_float(u.z << 16); f[5] = __uint_as_float(u.z & 0xFFFF0000u);
    f[6] = __uint_as_float(u.w << 16); f[7] = __uint_as_float(u.w & 0xFFFF0000u);
    uint32_t q[8];
    #pragma unroll
    for (int j = 0; j < 8; ++j) {
        int t = (int)rintf(f[j] * sinv);
        t = t > 127 ? 127 : (t < -127 ? -127 : t);
        q[j] = (uint32_t)t & 0xFFu;
    }
    uint2 o;
    o.x = q[0] | (q[1] << 8) | (q[2] << 16) | (q[3] << 24);
    o.y = q[4] | (q[5] << 8) | (q[6] << 16) | (q[7] << 24);
    xq2[(size_t)r * PER_REL + i] = o;
}

// ---------------------------------------------------------------------------
// K4: spmm2<Q8> — bucket-resident fused rowsort + SpMM + epilogue.
// Block = 64-row bucket, 512 thr. Stages the bucket's 4 relation runs into
// LDS counting-sorted by row (records rewritten to gather offsets; val
// pre-multiplied by scl[r]/127 when Q8), then quarter-wave-per-edge
// 2-stage-pipelined SpMM (64B int8 gathers when Q8) + fused epilogue.
// ---------------------------------------------------------------------------
template<int Q8>
__global__ __launch_bounds__(512) void spmm2_kernel(
    const uint2* __restrict__ xw2, const uint32_t* __restrict__ xq4,
    const int2* __restrict__ csr, const int* __restrict__ gstart,
    const float* __restrict__ scl, const float* __restrict__ bias,
    float* __restrict__ out)
{
    __shared__ int2 ebuf[NR][ECAP];     // 45056 B
    __shared__ int rcnt[NR][64];
    __shared__ int rofs[NR][64];
    __shared__ int rcur[NR][64];
    int tid = threadIdx.x, blk = blockIdx.x;
    int wv = __builtin_amdgcn_readfirstlane(tid >> 6);
    int lane = tid & 63;

    float sfac[NR];
    #pragma unroll
    for (int r = 0; r < NR; ++r)
        sfac[r] = Q8 ? scl[r] * (1.0f / 127.0f) : 1.0f;

    if (tid < 256) rcnt[tid >> 6][tid & 63] = 0;
    __syncthreads();

    // ---- load runs into registers + row histogram ----
    int sbeg[NR], cnt[NR], scnt[NR];
    int2 ed[NR][3];                     // ceil(ECAP/512)=3 per relation
    #pragma unroll
    for (int r = 0; r < NR; ++r) {
        int b = r * NB + blk;
        sbeg[r] = gstart[b];
        cnt[r]  = gstart[b + 1] - sbeg[r];
        scnt[r] = cnt[r] > ECAP ? ECAP : cnt[r];
        #pragma unroll
        for (int j = 0; j < 3; ++j) {
            int i = tid + j * 512;
            if (i < scnt[r]) {
                ed[r][j] = csr[sbeg[r] + i];
                atomicAdd(&rcnt[r][(ed[r][j].x >> 16) & 63], 1);
            }
        }
    }
    __syncthreads();

    // ---- per-relation 64-bin exscan (wave r handles relation r) ----
    if (wv < NR) {
        int c = rcnt[wv][lane];
        int inc = c;
        #pragma unroll
        for (int off = 1; off < 64; off <<= 1) {
            int u = __shfl_up(inc, off);
            if (lane >= off) inc += u;
        }
        rofs[wv][lane] = inc - c;
        rcur[wv][lane] = inc - c;
    }
    __syncthreads();

    // ---- scatter into ebuf row-sorted: (gather-ofs, val*sfac) ----
    #pragma unroll
    for (int r = 0; r < NR; ++r) {
        #pragma unroll
        for (int j = 0; j < 3; ++j) {
            int i = tid + j * 512;
            if (i < scnt[r]) {
                int rl = (ed[r][j].x >> 16) & 63;
                int slot = atomicAdd(&rcur[r][rl], 1);
                float v = __int_as_float(ed[r][j].y) * sfac[r];
                ebuf[r][slot] = make_int2((r * NN + (ed[r][j].x & 0xFFFF)) << 4,
                                          __float_as_int(v));
            }
        }
    }
    __syncthreads();

    // ---- SpMM: wave wv processes rows wv*8 .. wv*8+7 ----
    int e4 = lane >> 4, fq = lane & 15;
    float4 br[NR];
    #pragma unroll
    for (int r = 0; r < NR; ++r)
        br[r] = *(const float4*)&bias[r * DO + 4 * fq];

    for (int mi = 0; mi < 8; ++mi) {
        int m = wv * 8 + mi;
        int n = blk * 64 + m;
        if (n >= NN) break;             // wave-uniform

        int st[NR], dc[NR], dege[NR];
        int maxdeg = 0;
        #pragma unroll
        for (int r = 0; r < NR; ++r) {
            st[r] = rofs[r][m];
            dc[r] = rcnt[r][m];
            dege[r] = (dc[r] + 3) & ~3;
            maxdeg = max(maxdeg, dege[r]);
        }

        float a[NR][4];
        #pragma unroll
        for (int r = 0; r < NR; ++r)
            #pragma unroll
            for (int j = 0; j < 4; ++j) a[r][j] = 0.f;

        float vA[NR]; uint2 uA[NR];
        float vB[NR]; uint2 uB[NR];

        // stage issue k=0 into A
        #pragma unroll
        for (int r = 0; r < NR; ++r) {
            if (0 < dege[r]) {
                int e = e4; int ec = e < dc[r] ? e : dc[r] - 1;
                int2 cv = ebuf[r][st[r] + ec];
                vA[r] = (e < dc[r]) ? __int_as_float(cv.y) : 0.f;
                if (Q8) uA[r].x = xq4[cv.x + fq]; else uA[r] = xw2[cv.x + fq];
            } else { vA[r] = 0.f; uA[r] = make_uint2(0u, 0u); }
        }
        for (int k = 0; k < maxdeg; k += 8) {
            #pragma unroll
            for (int r = 0; r < NR; ++r) {          // issue k+4 -> B
                int kk = k + 4;
                if (kk < dege[r]) {
                    int e = kk + e4; int ec = e < dc[r] ? e : dc[r] - 1;
                    int2 cv = ebuf[r][st[r] + ec];
                    vB[r] = (e < dc[r]) ? __int_as_float(cv.y) : 0.f;
                    if (Q8) uB[r].x = xq4[cv.x + fq]; else uB[r] = xw2[cv.x + fq];
                } else { vB[r] = 0.f; uB[r] = make_uint2(0u, 0u); }
            }
            #pragma unroll
            for (int r = 0; r < NR; ++r) {          // consume A
                float v = vA[r];
                if (Q8) {
                    uint32_t u = uA[r].x;
                    a[r][0] = fmaf(v, (float)(((int)(u << 24)) >> 24), a[r][0]);
                    a[r][1] = fmaf(v, (float)(((int)(u << 16)) >> 24), a[r][1]);
                    a[r][2] = fmaf(v, (float)(((int)(u <<  8)) >> 24), a[r][2]);
                    a[r][3] = fmaf(v, (float)(((int)u) >> 24),         a[r][3]);
                } else {
                    a[r][0] = fmaf(v, __uint_as_float(uA[r].x << 16),         a[r][0]);
                    a[r][1] = fmaf(v, __uint_as_float(uA[r].x & 0xFFFF0000u), a[r][1]);
                    a[r][2] = fmaf(v, __uint_as_float(uA[r].y << 16),         a[r][2]);
                    a[r][3] = fmaf(v, __uint_as_float(uA[r].y & 0xFFFF0000u), a[r][3]);
                }
            }
            #pragma unroll
            for (int r = 0; r < NR; ++r) {          // issue k+8 -> A
                int kk = k + 8;
                if (kk < dege[r]) {
                    int e = kk + e4; int ec = e < dc[r] ? e : dc[r] - 1;
                    int2 cv = ebuf[r][st[r] + ec];
                    vA[r] = (e < dc[r]) ? __int_as_float(cv.y) : 0.f;
                    if (Q8) uA[r].x = xq4[cv.x + fq]; else uA[r] = xw2[cv.x + fq];
                } else { vA[r] = 0.f; uA[r] = make_uint2(0u, 0u); }
            }
            #pragma unroll
            for (int r = 0; r < NR; ++r) {          // consume B
                float v = vB[r];
                if (Q8) {
                    uint32_t u = uB[r].x;
                    a[r][0] = fmaf(v, (float)(((int)(u << 24)) >> 24), a[r][0]);
                    a[r][1] = fmaf(v, (float)(((int)(u << 16)) >> 24), a[r][1]);
                    a[r][2] = fmaf(v, (float)(((int)(u <<  8)) >> 24), a[r][2]);
                    a[r][3] = fmaf(v, (float)(((int)u) >> 24),         a[r][3]);
                } else {
                    a[r][0] = fmaf(v, __uint_as_float(uB[r].x << 16),         a[r][0]);
                    a[r][1] = fmaf(v, __uint_as_float(uB[r].x & 0xFFFF0000u), a[r][1]);
                    a[r][2] = fmaf(v, __uint_as_float(uB[r].y << 16),         a[r][2]);
                    a[r][3] = fmaf(v, __uint_as_float(uB[r].y & 0xFFFF0000u), a[r][3]);
                }
            }
        }

        // overflow tail (cnt>ECAP: ~never; scan unstaged edges from global)
        #pragma unroll
        for (int r = 0; r < NR; ++r) {
            if (cnt[r] > ECAP) {                    // wave-uniform
                for (int i = sbeg[r] + ECAP; i < sbeg[r] + cnt[r]; ++i) {
                    int2 cv = csr[i];
                    int rl = (cv.x >> 16) & 63;
                    float v = (rl == m && lane < 16)
                              ? __int_as_float(cv.y) * sfac[r] : 0.f;
                    int ofs = (int)((((size_t)r * NN + (cv.x & 0xFFFF)) << 4) + fq);
                    if (Q8) {
                        uint32_t u = xq4[ofs];
                        a[r][0] = fmaf(v, (float)(((int)(u << 24)) >> 24), a[r][0]);
                        a[r][1] = fmaf(v, (float)(((int)(u << 16)) >> 24), a[r][1]);
                        a[r][2] = fmaf(v, (float)(((int)(u <<  8)) >> 24), a[r][2]);
                        a[r][3] = fmaf(v, (float)(((int)u) >> 24),         a[r][3]);
                    } else {
                        uint2 u = xw2[ofs];
                        a[r][0] = fmaf(v, __uint_as_float(u.x << 16),         a[r][0]);
                        a[r][1] = fmaf(v, __uint_as_float(u.x & 0xFFFF0000u), a[r][1]);
                        a[r][2] = fmaf(v, __uint_as_float(u.y << 16),         a[r][2]);
                        a[r][3] = fmaf(v, __uint_as_float(u.y & 0xFFFF0000u), a[r][3]);
                    }
                }
            }
        }

        // epilogue: reduce edge-groups, bias+relu+sum, L2 normalize
        float t[4] = {0.f, 0.f, 0.f, 0.f};
        #pragma unroll
        for (int r = 0; r < NR; ++r) {
            #pragma unroll
            for (int j = 0; j < 4; ++j) {
                a[r][j] += __shfl_xor(a[r][j], 16);
                a[r][j] += __shfl_xor(a[r][j], 32);
            }
            t[0] += fmaxf(a[r][0] + br[r].x, 0.f);
            t[1] += fmaxf(a[r][1] + br[r].y, 0.f);
            t[2] += fmaxf(a[r][2] + br[r].z, 0.f);
            t[3] += fmaxf(a[r][3] + br[r].w, 0.f);
        }
        float s2 = t[0]*t[0] + t[1]*t[1] + t[2]*t[2] + t[3]*t[3];
        #pragma unroll
        for (int off = 8; off >= 1; off >>= 1) s2 += __shfl_xor(s2, off);
        float inv = 1.0f / fmaxf(sqrtf(s2), 1e-12f);
        if (lane < 16) {
            float4 o = make_float4(t[0]*inv, t[1]*inv, t[2]*inv, t[3]*inv);
            *(float4*)&out[(size_t)n * DO + 4 * fq] = o;
        }
    }
}

// ---------------------------------------------------------------------------
// Fallback path (small ws): R1 atomic-scatter pipeline.
// ---------------------------------------------------------------------------
__global__ __launch_bounds__(256) void gemm_kernel(
    const float* __restrict__ x, const float* __restrict__ W,
    __hip_bfloat16* __restrict__ xwb)
{
    __shared__ float Wl[DI * DO];
    for (int i = threadIdx.x; i < DI * DO; i += 256) Wl[i] = W[i];
    __syncthreads();

    int wv   = __builtin_amdgcn_readfirstlane((int)(threadIdx.x >> 6));
    int lane = threadIdx.x & 63;
    int n0   = blockIdx.x * 32 + wv * 8;
    if (n0 >= NN) return;
    int nrows = NN - n0; if (nrows > 8) nrows = 8;

    if (nrows == 8) {
        const float* xr = x + (size_t)n0 * DI;
        float acc[8] = {0.f,0.f,0.f,0.f,0.f,0.f,0.f,0.f};
        #pragma unroll 8
        for (int k = 0; k < DI; ++k) {
            float w = Wl[k * DO + lane];
            #pragma unroll
            for (int rr = 0; rr < 8; ++rr)
                acc[rr] = fmaf(xr[(size_t)rr * DI + k], w, acc[rr]);
        }
        #pragma unroll
        for (int rr = 0; rr < 8; ++rr)
            xwb[(size_t)(n0 + rr) * DO + lane] = __float2bfloat16(acc[rr]);
    } else {
        for (int rr = 0; rr < nrows; ++rr) {
            const float* xr = x + (size_t)(n0 + rr) * DI;
            float acc = 0.f;
            for (int k = 0; k < DI; ++k)
                acc = fmaf(xr[k], Wl[k * DO + lane], acc);
            xwb[(size_t)(n0 + rr) * DO + lane] = __float2bfloat16(acc);
        }
    }
}

__global__ __launch_bounds__(256) void scatter_kernel(
    const __hip_bfloat16* __restrict__ xwb, const float* __restrict__ vals,
    const int* __restrict__ rows, const int* __restrict__ cols,
    float* __restrict__ agg)
{
    const int nPairs = NE / 2;
    int gwave  = (blockIdx.x * 256 + threadIdx.x) >> 6;
    int half   = (threadIdx.x >> 5) & 1;
    int l32    = threadIdx.x & 31;
    int stride = gridDim.x * 4;
    const uint16_t* xw16 = reinterpret_cast<const uint16_t*>(xwb);
    for (int p = gwave; p < nPairs; p += stride) {
        int e = 2 * p + half;
        int row = rows[e]; int col = cols[e]; float v = vals[e];
        uint32_t packed = *reinterpret_cast<const uint32_t*>(
            xw16 + ((size_t)col << 6) + 2 * l32);
        float f0 = __uint_as_float(packed << 16);
        float f1 = __uint_as_float(packed & 0xFFFF0000u);
        float* dst = agg + ((size_t)row << 6) + 2 * l32;
        atomicAdd(dst,     v * f0);
        atomicAdd(dst + 1, v * f1);
    }
}

__global__ __launch_bounds__(256) void accum_kernel(
    float* __restrict__ agg, const float* __restrict__ b,
    float* __restrict__ out, int first)
{
    int i = blockIdx.x * 256 + threadIdx.x;
    if (i >= NN * DO) return;
    float v = agg[i] + b[i & (DO - 1)];
    agg[i] = 0.f;
    v = fmaxf(v, 0.f);
    out[i] = first ? v : (out[i] + v);
}

__global__ __launch_bounds__(256) void norm_kernel(float* __restrict__ out)
{
    int n = (blockIdx.x * 256 + threadIdx.x) >> 6;
    int lane = threadIdx.x & 63;
    if (n >= NN) return;
    size_t idx = (size_t)n * DO + lane;
    float t = out[idx];
    float s = t * t;
    #pragma unroll
    for (int off = 32; off >= 1; off >>= 1) s += __shfl_xor(s, off);
    out[idx] = t / fmaxf(sqrtf(s), 1e-12f);
}

extern "C" void kernel_launch(void* const* d_in, const int* in_sizes, int n_in,
                              void* d_out, int out_size, void* d_ws, size_t ws_size,
                              hipStream_t stream)
{
    const float* x    = (const float*)d_in[0];
    const float* W    = (const float*)d_in[1];
    const float* b    = (const float*)d_in[2];
    const float* vals = (const float*)d_in[3];
    const int*   rows = (const int*)d_in[4];
    const int*   cols = (const int*)d_in[5];
    float* out = (float*)d_out;
    char* ws = (char*)d_ws;

    // ws: xwb 25.6MB | csr 25.6MB | gtot | scl | gstart | gcur | wt | xq 12.8MB
    const size_t O_XW = 0;
    const size_t O_CS = O_XW + (size_t)NR * NN * DO * 2;
    const size_t O_GT = O_CS + (size_t)NR * NE * 8;
    const size_t O_SC = O_GT + (size_t)NBUCK * 4;       // 16 B (zeroed w/ gtot)
    const size_t O_GS = O_SC + 16;
    const size_t O_GC = O_GS + (size_t)(NBUCK + 1) * 4;
    const size_t O_WT = O_GC + (size_t)NBUCK * 4;       // bf16 W^T, 64KB
    const size_t O_XQ = O_WT + 65536;                   // int8 xw, 12.8MB
    const size_t NEED0 = O_XQ;                          // bf16 tier
    const size_t NEED1 = O_XQ + (size_t)NR * NN * DO;   // int8 tier

    if (ws_size >= NEED0) {
        __hip_bfloat16* xwb = (__hip_bfloat16*)(ws + O_XW);
        int2* csr   = (int2*)(ws + O_CS);
        int* gtot   = (int*)(ws + O_GT);
        float* scl  = (float*)(ws + O_SC);
        int* gstart = (int*)(ws + O_GS);
        int* gcur   = (int*)(ws + O_GC);
        uint16_t* wt = (uint16_t*)(ws + O_WT);
        char* xq    = ws + O_XQ;
        bool q8 = (ws_size >= NEED1);

        hipMemsetAsync(gtot, 0, (size_t)NBUCK * 4 + 16, stream);
        prep_kernel<<<dim3(256), dim3(256), 0, stream>>>(W, rows, wt, gtot);
        bases_kernel<<<dim3(1), dim3(512), 0, stream>>>(gtot, gstart, gcur);
        gemm_place_kernel<<<dim3(GEMMB + PWG * NR), dim3(512), 0, stream>>>(
            x, (const uint4*)wt, (uint16_t*)xwb,
            rows, cols, vals, gcur, csr);
        if (q8) {
            maxred_kernel<<<dim3(64, NR), dim3(256), 0, stream>>>(
                (const uint4*)xwb, scl);
            quant_kernel<<<dim3((NN * DO / 8 + 255) / 256, NR), dim3(256), 0, stream>>>(
                (const uint4*)xwb, (uint2*)xq, scl);
            spmm2_kernel<1><<<dim3(NB), dim3(512), 0, stream>>>(
                (const uint2*)xwb, (const uint32_t*)xq, csr, gstart, scl, b, out);
        } else {
            spmm2_kernel<0><<<dim3(NB), dim3(512), 0, stream>>>(
                (const uint2*)xwb, (const uint32_t*)xq, csr, gstart, scl, b, out);
        }
    } else {
        // sequential atomic-scatter fallback (19.2MB)
        __hip_bfloat16* xwb = (__hip_bfloat16*)ws;
        float* agg = (float*)(ws + (size_t)NN * DO * 2);
        hipMemsetAsync(agg, 0, (size_t)NN * DO * 4, stream);
        for (int r = 0; r < NR; ++r) {
            gemm_kernel<<<dim3((NN + 31) / 32), dim3(256), 0, stream>>>(
                x, W + (size_t)r * DI * DO, xwb);
            scatter_kernel<<<dim3(2048), dim3(256), 0, stream>>>(
                xwb, vals + (size_t)r * NE, rows + (size_t)r * NE,
                cols + (size_t)r * NE, agg);
            accum_kernel<<<dim3((NN * DO + 255) / 256), dim3(256), 0, stream>>>(
                agg, b + (size_t)r * DO, out, r == 0);
        }
        norm_kernel<<<dim3((NN * DO + 255) / 256), dim3(256), 0, stream>>>(out);
    }
}

// Round 16
// 162.732 us; speedup vs baseline: 1.7942x; 1.1518x over previous
//
#include <hip/hip_runtime.h>
#include <hip/hip_bf16.h>
#include <stdint.h>

#define NN 50000   // nodes
#define DI 128     // input features
#define DO 64      // output features
#define NE 800000  // edges per relation
#define NR 4       // relations
#define NB 782     // ceil(NN/64) buckets per relation
#define NBUCK (NR*NB)   // 3128 buckets total
#define PCHUNK 7168     // edges per place workgroup
#define PWG ((NE + PCHUNK - 1) / PCHUNK)   // 112 per relation
#define GEMMB ((NN + 127) / 128)   // 391 gemm blocks
#define ECAP 1408       // spmm2 per-relation bucket-run capacity (mean 1024, +12 sigma)

typedef short short8 __attribute__((ext_vector_type(8)));
typedef float f32x4  __attribute__((ext_vector_type(4)));
union FragU { uint4 u; short8 s; };

__device__ __forceinline__ uint32_t bfb(float f)
{
    __hip_bfloat16 h = __float2bfloat16(f);
    return (uint32_t)*reinterpret_cast<unsigned short*>(&h);
}

// ---------------------------------------------------------------------------
// Block-wide exclusive scan of a[0..N) in LDS. BLK threads, PER elems/thread.
// ---------------------------------------------------------------------------
template<int N, int PER, int BLK>
__device__ inline void block_exscan(int* a)
{
    __shared__ int wsum[BLK / 64];
    int tid = threadIdx.x;
    int base = tid * PER;
    int v[PER]; int s = 0;
    #pragma unroll
    for (int j = 0; j < PER; ++j) {
        int idx = base + j;
        int x = (idx < N) ? a[idx] : 0;
        v[j] = s; s += x;
    }
    int lane = tid & 63, wv = tid >> 6;
    int inc = s;
    #pragma unroll
    for (int off = 1; off < 64; off <<= 1) {
        int u = __shfl_up(inc, off);
        if (lane >= off) inc += u;
    }
    if (lane == 63) wsum[wv] = inc;
    __syncthreads();
    int woff = 0;
    for (int w = 0; w < wv; ++w) woff += wsum[w];
    int tb = woff + inc - s;
    #pragma unroll
    for (int j = 0; j < PER; ++j) {
        int idx = base + j;
        if (idx < N) a[idx] = tb + v[j];
    }
}

// ---------------------------------------------------------------------------
// K1: wtrans (blocks [0,128)) || bhist (blocks [128,256)).
// ---------------------------------------------------------------------------
__global__ __launch_bounds__(256) void prep_kernel(
    const float* __restrict__ W, const int* __restrict__ rows,
    uint16_t* __restrict__ wt, int* __restrict__ gtot)
{
    __shared__ int h[NB];
    int bid = blockIdx.x, tid = threadIdx.x;

    if (bid < 128) {
        int i = bid * 256 + tid;   // exactly 32768
        int r = i >> 13;
        int k = (i >> 6) & 127;
        int n = i & 63;
        wt[((size_t)(r * DO + n) << 7) + k] = (uint16_t)bfb(W[i]);
    } else {
        int bb = bid - 128;
        int r = bb >> 5, sub = bb & 31;
        for (int i = tid; i < NB; i += 256) h[i] = 0;
        __syncthreads();
        const int4* rr4 = (const int4*)(rows + (size_t)r * NE);
        for (int k = sub * 256 + tid; k < NE / 4; k += 32 * 256) {
            int4 v = rr4[k];
            atomicAdd(&h[v.x >> 6], 1);
            atomicAdd(&h[v.y >> 6], 1);
            atomicAdd(&h[v.z >> 6], 1);
            atomicAdd(&h[v.w >> 6], 1);
        }
        __syncthreads();
        int* gt = gtot + r * NB;
        for (int i = tid; i < NB; i += 256)
            if (h[i]) atomicAdd(&gt[i], h[i]);
    }
}

// ---------------------------------------------------------------------------
// K2: scan bucket totals -> gstart[0..NBUCK] + gcur copy. One block.
// ---------------------------------------------------------------------------
__global__ __launch_bounds__(512) void bases_kernel(
    const int* __restrict__ gtot, int* __restrict__ gstart,
    int* __restrict__ gcur)
{
    __shared__ int a[NBUCK + 1];
    int tid = threadIdx.x;
    for (int i = tid; i < NBUCK + 1; i += 512) a[i] = (i < NBUCK) ? gtot[i] : 0;
    __syncthreads();
    block_exscan<NBUCK + 1, 7, 512>(a);
    __syncthreads();
    for (int i = tid; i < NBUCK + 1; i += 512) {
        gstart[i] = a[i];
        if (i < NBUCK) gcur[i] = a[i];
    }
}

// ---------------------------------------------------------------------------
// K3: gemm (blocks [0,GEMMB)) || place (blocks [GEMMB, GEMMB+PWG*NR)).
// gemm: x f32 -> bf16 fragments in-register; MFMA 16x16x32; LDS-staged stores.
// place: bucket counting-sort of a PCHUNK chunk; record col:16|rowlow:6|bkt:10.
// ---------------------------------------------------------------------------
__global__ __launch_bounds__(512) void gemm_place_kernel(
    const float* __restrict__ x, const uint4* __restrict__ wt4,
    uint16_t* __restrict__ xwb,
    const int* __restrict__ rows, const int* __restrict__ cols,
    const float* __restrict__ vals, int* __restrict__ gcur,
    int2* __restrict__ csr)
{
    __shared__ __align__(16) char smem[63616];
    int tid = threadIdx.x;

    if (blockIdx.x < GEMMB) {
        // ================= gemm role =================
        uint16_t* tile = (uint16_t*)smem;           // 16 KB
        int wv = __builtin_amdgcn_readfirstlane(tid >> 6);
        int lane = tid & 63;
        int n0 = blockIdx.x * 128 + wv * 16;
        int m16 = lane & 15, g = lane >> 4;
        bool act = (n0 < NN);                       // wave-uniform

        FragU af[4];
        if (act) {
            const float4* x4 = (const float4*)x;
            size_t rb = ((size_t)(n0 + m16) * DI) >> 2;
            #pragma unroll
            for (int ks = 0; ks < 4; ++ks) {
                float4 f0 = x4[rb + ks * 8 + g * 2];
                float4 f1 = x4[rb + ks * 8 + g * 2 + 1];
                af[ks].u.x = bfb(f0.x) | (bfb(f0.y) << 16);
                af[ks].u.y = bfb(f0.z) | (bfb(f0.w) << 16);
                af[ks].u.z = bfb(f1.x) | (bfb(f1.y) << 16);
                af[ks].u.w = bfb(f1.z) | (bfb(f1.w) << 16);
            }
        }

        int nrows = NN - blockIdx.x * 128; if (nrows > 128) nrows = 128;

        for (int r = 0; r < NR; ++r) {
            if (act) {
                #pragma unroll
                for (int ct = 0; ct < 4; ++ct) {
                    f32x4 acc = {0.f, 0.f, 0.f, 0.f};
                    #pragma unroll
                    for (int ks = 0; ks < 4; ++ks) {
                        FragU b;
                        b.u = wt4[(size_t)((r * DO + ct * 16 + m16) * 16) + ks * 4 + g];
                        acc = __builtin_amdgcn_mfma_f32_16x16x32_bf16(
                            af[ks].s, b.s, acc, 0, 0, 0);
                    }
                    #pragma unroll
                    for (int j = 0; j < 4; ++j)
                        tile[(wv * 16 + g * 4 + j) * 64 + ct * 16 + m16] =
                            (uint16_t)bfb(acc[j]);
                }
            }
            __syncthreads();
            uint4* dst = (uint4*)(xwb + ((size_t)r * NN + blockIdx.x * 128) * 64);
            int tot = nrows * 8;
            for (int i = tid; i < tot; i += 512)
                dst[i] = ((const uint4*)tile)[i];
            __syncthreads();
        }
        return;
    }

    // ================= place role =================
    int* lofs  = (int*)smem;                        // (NB+1)*4 = 3132
    int* gbase = (int*)(smem + 3136);               // NB*4 = 3128
    int2* stag = (int2*)(smem + 6272);              // PCHUNK*8 = 57344
    int pb = blockIdx.x - GEMMB;
    int r = pb / PWG;
    int chunk = pb - r * PWG;
    int e0 = chunk * PCHUNK;
    int cnt = NE - e0; if (cnt > PCHUNK) cnt = PCHUNK;
    const int*   rr = rows + (size_t)r * NE + e0;
    const int*   cc = cols + (size_t)r * NE + e0;
    const float* vv = vals + (size_t)r * NE + e0;

    for (int i = tid; i <= NB; i += 512) lofs[i] = 0;
    __syncthreads();
    for (int k = tid; k < cnt; k += 512) atomicAdd(&lofs[rr[k] >> 6], 1);
    __syncthreads();
    block_exscan<NB + 1, 2, 512>(lofs);
    __syncthreads();
    for (int b = tid; b < NB; b += 512) {
        int c = lofs[b + 1] - lofs[b];
        if (c > 0) gbase[b] = atomicAdd(&gcur[r * NB + b], c);
    }
    __syncthreads();
    for (int k = tid; k < cnt; k += 512) {
        int row = rr[k];
        int b = row >> 6;
        int slot = atomicAdd(&lofs[b], 1);
        stag[slot] = make_int2((cc[k] & 0xFFFF) | ((row & 63) << 16) | (b << 22),
                               __float_as_int(vv[k]));
    }
    __syncthreads();
    for (int i = tid; i < cnt; i += 512) {
        int2 t = stag[i];
        unsigned b2 = ((unsigned)t.x) >> 22;
        int start = b2 ? lofs[b2 - 1] : 0;
        csr[gbase[b2] + (i - start)] = t;
    }
}

// ---------------------------------------------------------------------------
// K4: spmm2 — bucket-resident fused rowsort + SpMM + epilogue.
// Block = 64-row bucket, 512 thr (8 waves). Stages the bucket's 4 relation
// runs into LDS (counting-sorted by row, records rewritten to precomputed
// gather offsets), then each wave processes 8 rows: quarter-wave per edge,
// 2-stage pipeline, metadata from LDS, fused bias/relu/sum/L2-normalize.
// ---------------------------------------------------------------------------
__global__ __launch_bounds__(512) void spmm2_kernel(
    const uint2* __restrict__ xw2, const int2* __restrict__ csr,
    const int* __restrict__ gstart, const float* __restrict__ bias,
    float* __restrict__ out)
{
    __shared__ int2 ebuf[NR][ECAP];     // 45056 B
    __shared__ int rcnt[NR][64];
    __shared__ int rofs[NR][64];
    __shared__ int rcur[NR][64];
    int tid = threadIdx.x, blk = blockIdx.x;
    int wv = __builtin_amdgcn_readfirstlane(tid >> 6);
    int lane = tid & 63;

    if (tid < 256) rcnt[tid >> 6][tid & 63] = 0;
    __syncthreads();

    // ---- load runs into registers + row histogram ----
    int sbeg[NR], cnt[NR], scnt[NR];
    int2 ed[NR][3];                     // ceil(ECAP/512)=3 per relation
    #pragma unroll
    for (int r = 0; r < NR; ++r) {
        int b = r * NB + blk;
        sbeg[r] = gstart[b];
        cnt[r]  = gstart[b + 1] - sbeg[r];
        scnt[r] = cnt[r] > ECAP ? ECAP : cnt[r];
        #pragma unroll
        for (int j = 0; j < 3; ++j) {
            int i = tid + j * 512;
            if (i < scnt[r]) {
                ed[r][j] = csr[sbeg[r] + i];
                atomicAdd(&rcnt[r][(ed[r][j].x >> 16) & 63], 1);
            }
        }
    }
    __syncthreads();

    // ---- per-relation 64-bin exscan (wave r handles relation r) ----
    if (wv < NR) {
        int c = rcnt[wv][lane];         // lanes 0..63 = rows
        int inc = c;
        #pragma unroll
        for (int off = 1; off < 64; off <<= 1) {
            int u = __shfl_up(inc, off);
            if (lane >= off) inc += u;
        }
        rofs[wv][lane] = inc - c;
        rcur[wv][lane] = inc - c;
    }
    __syncthreads();

    // ---- scatter into ebuf row-sorted, rewriting to gather offsets ----
    #pragma unroll
    for (int r = 0; r < NR; ++r) {
        #pragma unroll
        for (int j = 0; j < 3; ++j) {
            int i = tid + j * 512;
            if (i < scnt[r]) {
                int rl = (ed[r][j].x >> 16) & 63;
                int slot = atomicAdd(&rcur[r][rl], 1);
                ebuf[r][slot] = make_int2((r * NN + (ed[r][j].x & 0xFFFF)) << 4,
                                          ed[r][j].y);
            }
        }
    }
    __syncthreads();

    // ---- SpMM: wave wv processes rows wv*8 .. wv*8+7 ----
    int e4 = lane >> 4, fq = lane & 15;
    float4 br[NR];
    #pragma unroll
    for (int r = 0; r < NR; ++r)
        br[r] = *(const float4*)&bias[r * DO + 4 * fq];

    for (int mi = 0; mi < 8; ++mi) {
        int m = wv * 8 + mi;
        int n = blk * 64 + m;
        if (n >= NN) break;             // wave-uniform

        int st[NR], dc[NR], dege[NR];
        int maxdeg = 0;
        #pragma unroll
        for (int r = 0; r < NR; ++r) {
            st[r] = rofs[r][m];
            dc[r] = rcnt[r][m];
            dege[r] = (dc[r] + 3) & ~3;
            maxdeg = max(maxdeg, dege[r]);
        }

        float a[NR][4];
        #pragma unroll
        for (int r = 0; r < NR; ++r)
            #pragma unroll
            for (int j = 0; j < 4; ++j) a[r][j] = 0.f;

        float vA[NR]; uint2 uA[NR];
        float vB[NR]; uint2 uB[NR];

        // stage issue k=0 into A
        #pragma unroll
        for (int r = 0; r < NR; ++r) {
            if (0 < dege[r]) {
                int e = e4; int ec = e < dc[r] ? e : dc[r] - 1;
                int2 cv = ebuf[r][st[r] + ec];
                vA[r] = (e < dc[r]) ? __int_as_float(cv.y) : 0.f;
                uA[r] = xw2[cv.x + fq];
            } else { vA[r] = 0.f; uA[r] = make_uint2(0u, 0u); }
        }
        for (int k = 0; k < maxdeg; k += 8) {
            #pragma unroll
            for (int r = 0; r < NR; ++r) {          // issue k+4 -> B
                int kk = k + 4;
                if (kk < dege[r]) {
                    int e = kk + e4; int ec = e < dc[r] ? e : dc[r] - 1;
                    int2 cv = ebuf[r][st[r] + ec];
                    vB[r] = (e < dc[r]) ? __int_as_float(cv.y) : 0.f;
                    uB[r] = xw2[cv.x + fq];
                } else { vB[r] = 0.f; uB[r] = make_uint2(0u, 0u); }
            }
            #pragma unroll
            for (int r = 0; r < NR; ++r) {          // consume A
                float v = vA[r];
                a[r][0] = fmaf(v, __uint_as_float(uA[r].x << 16),         a[r][0]);
                a[r][1] = fmaf(v, __uint_as_float(uA[r].x & 0xFFFF0000u), a[r][1]);
                a[r][2] = fmaf(v, __uint_as_float(uA[r].y << 16),         a[r][2]);
                a[r][3] = fmaf(v, __uint_as_float(uA[r].y & 0xFFFF0000u), a[r][3]);
            }
            #pragma unroll
            for (int r = 0; r < NR; ++r) {          // issue k+8 -> A
                int kk = k + 8;
                if (kk < dege[r]) {
                    int e = kk + e4; int ec = e < dc[r] ? e : dc[r] - 1;
                    int2 cv = ebuf[r][st[r] + ec];
                    vA[r] = (e < dc[r]) ? __int_as_float(cv.y) : 0.f;
                    uA[r] = xw2[cv.x + fq];
                } else { vA[r] = 0.f; uA[r] = make_uint2(0u, 0u); }
            }
            #pragma unroll
            for (int r = 0; r < NR; ++r) {          // consume B
                float v = vB[r];
                a[r][0] = fmaf(v, __uint_as_float(uB[r].x << 16),         a[r][0]);
                a[r][1] = fmaf(v, __uint_as_float(uB[r].x & 0xFFFF0000u), a[r][1]);
                a[r][2] = fmaf(v, __uint_as_float(uB[r].y << 16),         a[r][2]);
                a[r][3] = fmaf(v, __uint_as_float(uB[r].y & 0xFFFF0000u), a[r][3]);
            }
        }

        // overflow tail (cnt>ECAP: ~never; scan unstaged edges from global)
        #pragma unroll
        for (int r = 0; r < NR; ++r) {
            if (cnt[r] > ECAP) {                    // wave-uniform
                for (int i = sbeg[r] + ECAP; i < sbeg[r] + cnt[r]; ++i) {
                    int2 cv = csr[i];
                    int rl = (cv.x >> 16) & 63;
                    float v = (rl == m && lane < 16) ? __int_as_float(cv.y) : 0.f;
                    uint2 u = xw2[(((size_t)r * NN + (cv.x & 0xFFFF)) << 4) + fq];
                    a[r][0] = fmaf(v, __uint_as_float(u.x << 16),         a[r][0]);
                    a[r][1] = fmaf(v, __uint_as_float(u.x & 0xFFFF0000u), a[r][1]);
                    a[r][2] = fmaf(v, __uint_as_float(u.y << 16),         a[r][2]);
                    a[r][3] = fmaf(v, __uint_as_float(u.y & 0xFFFF0000u), a[r][3]);
                }
            }
        }

        // epilogue: reduce edge-groups, bias+relu+sum, L2 normalize
        float t[4] = {0.f, 0.f, 0.f, 0.f};
        #pragma unroll
        for (int r = 0; r < NR; ++r) {
            #pragma unroll
            for (int j = 0; j < 4; ++j) {
                a[r][j] += __shfl_xor(a[r][j], 16);
                a[r][j] += __shfl_xor(a[r][j], 32);
            }
            t[0] += fmaxf(a[r][0] + br[r].x, 0.f);
            t[1] += fmaxf(a[r][1] + br[r].y, 0.f);
            t[2] += fmaxf(a[r][2] + br[r].z, 0.f);
            t[3] += fmaxf(a[r][3] + br[r].w, 0.f);
        }
        float s2 = t[0]*t[0] + t[1]*t[1] + t[2]*t[2] + t[3]*t[3];
        #pragma unroll
        for (int off = 8; off >= 1; off >>= 1) s2 += __shfl_xor(s2, off);
        float inv = 1.0f / fmaxf(sqrtf(s2), 1e-12f);
        if (lane < 16) {
            float4 o = make_float4(t[0]*inv, t[1]*inv, t[2]*inv, t[3]*inv);
            *(float4*)&out[(size_t)n * DO + 4 * fq] = o;
        }
    }
}

// ---------------------------------------------------------------------------
// Fallback path (small ws): R1 atomic-scatter pipeline.
// ---------------------------------------------------------------------------
__global__ __launch_bounds__(256) void gemm_kernel(
    const float* __restrict__ x, const float* __restrict__ W,
    __hip_bfloat16* __restrict__ xwb)
{
    __shared__ float Wl[DI * DO];
    for (int i = threadIdx.x; i < DI * DO; i += 256) Wl[i] = W[i];
    __syncthreads();

    int wv   = __builtin_amdgcn_readfirstlane((int)(threadIdx.x >> 6));
    int lane = threadIdx.x & 63;
    int n0   = blockIdx.x * 32 + wv * 8;
    if (n0 >= NN) return;
    int nrows = NN - n0; if (nrows > 8) nrows = 8;

    if (nrows == 8) {
        const float* xr = x + (size_t)n0 * DI;
        float acc[8] = {0.f,0.f,0.f,0.f,0.f,0.f,0.f,0.f};
        #pragma unroll 8
        for (int k = 0; k < DI; ++k) {
            float w = Wl[k * DO + lane];
            #pragma unroll
            for (int rr = 0; rr < 8; ++rr)
                acc[rr] = fmaf(xr[(size_t)rr * DI + k], w, acc[rr]);
        }
        #pragma unroll
        for (int rr = 0; rr < 8; ++rr)
            xwb[(size_t)(n0 + rr) * DO + lane] = __float2bfloat16(acc[rr]);
    } else {
        for (int rr = 0; rr < nrows; ++rr) {
            const float* xr = x + (size_t)(n0 + rr) * DI;
            float acc = 0.f;
            for (int k = 0; k < DI; ++k)
                acc = fmaf(xr[k], Wl[k * DO + lane], acc);
            xwb[(size_t)(n0 + rr) * DO + lane] = __float2bfloat16(acc);
        }
    }
}

__global__ __launch_bounds__(256) void scatter_kernel(
    const __hip_bfloat16* __restrict__ xwb, const float* __restrict__ vals,
    const int* __restrict__ rows, const int* __restrict__ cols,
    float* __restrict__ agg)
{
    const int nPairs = NE / 2;
    int gwave  = (blockIdx.x * 256 + threadIdx.x) >> 6;
    int half   = (threadIdx.x >> 5) & 1;
    int l32    = threadIdx.x & 31;
    int stride = gridDim.x * 4;
    const uint16_t* xw16 = reinterpret_cast<const uint16_t*>(xwb);
    for (int p = gwave; p < nPairs; p += stride) {
        int e = 2 * p + half;
        int row = rows[e]; int col = cols[e]; float v = vals[e];
        uint32_t packed = *reinterpret_cast<const uint32_t*>(
            xw16 + ((size_t)col << 6) + 2 * l32);
        float f0 = __uint_as_float(packed << 16);
        float f1 = __uint_as_float(packed & 0xFFFF0000u);
        float* dst = agg + ((size_t)row << 6) + 2 * l32;
        atomicAdd(dst,     v * f0);
        atomicAdd(dst + 1, v * f1);
    }
}

__global__ __launch_bounds__(256) void accum_kernel(
    float* __restrict__ agg, const float* __restrict__ b,
    float* __restrict__ out, int first)
{
    int i = blockIdx.x * 256 + threadIdx.x;
    if (i >= NN * DO) return;
    float v = agg[i] + b[i & (DO - 1)];
    agg[i] = 0.f;
    v = fmaxf(v, 0.f);
    out[i] = first ? v : (out[i] + v);
}

__global__ __launch_bounds__(256) void norm_kernel(float* __restrict__ out)
{
    int n = (blockIdx.x * 256 + threadIdx.x) >> 6;
    int lane = threadIdx.x & 63;
    if (n >= NN) return;
    size_t idx = (size_t)n * DO + lane;
    float t = out[idx];
    float s = t * t;
    #pragma unroll
    for (int off = 32; off >= 1; off >>= 1) s += __shfl_xor(s, off);
    out[idx] = t / fmaxf(sqrtf(s), 1e-12f);
}

extern "C" void kernel_launch(void* const* d_in, const int* in_sizes, int n_in,
                              void* d_out, int out_size, void* d_ws, size_t ws_size,
                              hipStream_t stream)
{
    const float* x    = (const float*)d_in[0];
    const float* W    = (const float*)d_in[1];
    const float* b    = (const float*)d_in[2];
    const float* vals = (const float*)d_in[3];
    const int*   rows = (const int*)d_in[4];
    const int*   cols = (const int*)d_in[5];
    float* out = (float*)d_out;
    char* ws = (char*)d_ws;

    // ws: xwb 25.6MB | csr 25.6MB | gtot | gstart | gcur | wt
    const size_t O_XW = 0;
    const size_t O_CS = O_XW + (size_t)NR * NN * DO * 2;
    const size_t O_GT = O_CS + (size_t)NR * NE * 8;
    const size_t O_GS = O_GT + (size_t)NBUCK * 4;
    const size_t O_GC = O_GS + (size_t)(NBUCK + 1) * 4;
    const size_t O_WT = O_GC + (size_t)NBUCK * 4;     // bf16 W^T, 64KB
    const size_t NEED = O_WT + 65536;

    if (ws_size >= NEED) {
        __hip_bfloat16* xwb = (__hip_bfloat16*)(ws + O_XW);
        int2* csr   = (int2*)(ws + O_CS);
        int* gtot   = (int*)(ws + O_GT);
        int* gstart = (int*)(ws + O_GS);
        int* gcur   = (int*)(ws + O_GC);
        uint16_t* wt = (uint16_t*)(ws + O_WT);

        hipMemsetAsync(gtot, 0, (size_t)NBUCK * 4, stream);
        prep_kernel<<<dim3(256), dim3(256), 0, stream>>>(W, rows, wt, gtot);
        bases_kernel<<<dim3(1), dim3(512), 0, stream>>>(gtot, gstart, gcur);
        gemm_place_kernel<<<dim3(GEMMB + PWG * NR), dim3(512), 0, stream>>>(
            x, (const uint4*)wt, (uint16_t*)xwb,
            rows, cols, vals, gcur, csr);
        spmm2_kernel<<<dim3(NB), dim3(512), 0, stream>>>(
            (const uint2*)xwb, csr, gstart, b, out);
    } else {
        // sequential atomic-scatter fallback (19.2MB)
        __hip_bfloat16* xwb = (__hip_bfloat16*)ws;
        float* agg = (float*)(ws + (size_t)NN * DO * 2);
        hipMemsetAsync(agg, 0, (size_t)NN * DO * 4, stream);
        for (int r = 0; r < NR; ++r) {
            gemm_kernel<<<dim3((NN + 31) / 32), dim3(256), 0, stream>>>(
                x, W + (size_t)r * DI * DO, xwb);
            scatter_kernel<<<dim3(2048), dim3(256), 0, stream>>>(
                xwb, vals + (size_t)r * NE, rows + (size_t)r * NE,
                cols + (size_t)r * NE, agg);
            accum_kernel<<<dim3((NN * DO + 255) / 256), dim3(256), 0, stream>>>(
                agg, b + (size_t)r * DO, out, r == 0);
        }
        norm_kernel<<<dim3((NN * DO + 255) / 256), dim3(256), 0, stream>>>(out);
    }
}